// Round 2
// baseline (92.725 us; speedup 1.0000x reference)
//
#include <hip/hip_runtime.h>

#define NPTS 8192
#define BLOCK 256
#define IB 16                   // i's per block
#define NBLK (NPTS / IB)        // 512 blocks
#define TJ 2048                 // j-tile staged in LDS
#define NTILES (NPTS / TJ)      // 4
#define RPT (TJ / BLOCK)        // 8 j's per thread per tile

// closeness^2 = exp(-100*d2)  ->  exp2(C1*d2),  C1 = -100*log2(e)
#define C1 (-144.26950408889634f)
#define K2 (288.53900817779268f)    // -2*C1
// out = s*exp(-20*pen)  ->  exp2(C2*pen)
#define C2 (-28.853900817779268f)

__global__ __launch_bounds__(BLOCK, 2) void softnms_kernel(
    const float* __restrict__ src, const float* __restrict__ tgt,
    const float* __restrict__ scores, float* __restrict__ out)
{
    __shared__ float lsrc[TJ * 3];              // 24 KB
    __shared__ float ltgt[TJ * 3];              // 24 KB
    __shared__ float lsc[TJ];                   //  8 KB
    __shared__ float lid[IB * 7];               // i-data broadcast buffer
    __shared__ float red[(BLOCK / 64) * IB];    // cross-wave reduction

    const int t  = threadIdx.x;
    const int i0 = blockIdx.x * IB;

    // Stage i-data through LDS so it lands in VGPRs (not 112 SGPRs).
    if (t < IB) {
        int i = i0 + t;
        lid[t * 7 + 0] = src[i * 3 + 0];
        lid[t * 7 + 1] = src[i * 3 + 1];
        lid[t * 7 + 2] = src[i * 3 + 2];
        lid[t * 7 + 3] = tgt[i * 3 + 0];
        lid[t * 7 + 4] = tgt[i * 3 + 1];
        lid[t * 7 + 5] = tgt[i * 3 + 2];
        lid[t * 7 + 6] = scores[i];
    }
    __syncthreads();

    float pix[IB], piy[IB], piz[IB], qix[IB], qiy[IB], qiz[IB];
    float si[IB], ci[IB], acc[IB];
    #pragma unroll
    for (int k = 0; k < IB; k++) {
        pix[k] = lid[k * 7 + 0];
        piy[k] = lid[k * 7 + 1];
        piz[k] = lid[k * 7 + 2];
        qix[k] = lid[k * 7 + 3];
        qiy[k] = lid[k * 7 + 4];
        qiz[k] = lid[k * 7 + 5];
        si[k]  = lid[k * 7 + 6];
        float ni = pix[k] * pix[k] + piy[k] * piy[k] + piz[k] * piz[k]
                 + qix[k] * qix[k] + qiy[k] * qiy[k] + qiz[k] * qiz[k];
        ci[k]  = C1 * ni;
        acc[k] = 0.0f;
    }

    for (int tile = 0; tile < NTILES; tile++) {
        const int j0 = tile * TJ;

        // ---- stage j-tile (coalesced float4 global -> contiguous LDS) ----
        {
            const float4* s4 = (const float4*)src + (j0 * 3) / 4;
            const float4* t4 = (const float4*)tgt + (j0 * 3) / 4;
            const float4* c4 = (const float4*)scores + j0 / 4;
            float4* ls = (float4*)lsrc;
            float4* lt = (float4*)ltgt;
            float4* lc = (float4*)lsc;
            #pragma unroll
            for (int r = 0; r < (TJ * 3) / 4 / BLOCK; r++) {   // 6
                ls[t + r * BLOCK] = s4[t + r * BLOCK];
                lt[t + r * BLOCK] = t4[t + r * BLOCK];
            }
            #pragma unroll
            for (int r = 0; r < TJ / 4 / BLOCK; r++) {         // 2
                lc[t + r * BLOCK] = c4[t + r * BLOCK];
            }
        }
        __syncthreads();

        // ---- compute: each thread walks RPT j's, 16 i's each ----
        #pragma unroll 2
        for (int r = 0; r < RPT; r++) {
            const int j = r * BLOCK + t;
            float ax = lsrc[j * 3 + 0];
            float ay = lsrc[j * 3 + 1];
            float az = lsrc[j * 3 + 2];
            float bx = ltgt[j * 3 + 0];
            float by = ltgt[j * 3 + 1];
            float bz = ltgt[j * 3 + 2];
            float sj = lsc[j];
            float nj = ax * ax + ay * ay + az * az
                     + bx * bx + by * by + bz * bz;
            float cj = C1 * nj;
            #pragma unroll
            for (int k = 0; k < IB; k++) {
                float dot = pix[k] * ax + piy[k] * ay + piz[k] * az
                          + qix[k] * bx + qiy[k] * by + qiz[k] * bz;
                float arg = fmaf(K2, dot, ci[k] + cj);
                float cl  = __builtin_amdgcn_exp2f(arg);
                acc[k] += (sj > si[k]) ? cl : 0.0f;
            }
        }
        __syncthreads();
    }

    // ---- reduce acc[k] across the block, finalize inline ----
    const int lane = t & 63;
    const int wid  = t >> 6;
    #pragma unroll
    for (int k = 0; k < IB; k++) {
        float v = acc[k];
        v += __shfl_xor(v, 32);
        v += __shfl_xor(v, 16);
        v += __shfl_xor(v, 8);
        v += __shfl_xor(v, 4);
        v += __shfl_xor(v, 2);
        v += __shfl_xor(v, 1);
        if (lane == 0) red[wid * IB + k] = v;
    }
    __syncthreads();
    if (t < IB) {
        float p = red[0 * IB + t] + red[1 * IB + t]
                + red[2 * IB + t] + red[3 * IB + t];
        out[i0 + t] = scores[i0 + t] * __builtin_amdgcn_exp2f(C2 * p);
    }
}

extern "C" void kernel_launch(void* const* d_in, const int* in_sizes, int n_in,
                              void* d_out, int out_size, void* d_ws, size_t ws_size,
                              hipStream_t stream) {
    const float* src    = (const float*)d_in[0];
    const float* tgt    = (const float*)d_in[1];
    const float* scores = (const float*)d_in[2];
    float* out = (float*)d_out;

    softnms_kernel<<<NBLK, BLOCK, 0, stream>>>(src, tgt, scores, out);
}

// Round 3
// 84.778 us; speedup vs baseline: 1.0937x; 1.0937x over previous
//
#include <hip/hip_runtime.h>

#define NPTS 8192
#define IBLK 16                  // i's per block
#define IPT 8                    // i's per thread (block split into 2 i-halves)
#define BLOCK 512                // 2 halves x 256 j-threads
#define JT 256                   // j-threads per half
#define NBLK (NPTS / IBLK)       // 512 blocks = exactly 2 per CU
#define TJ 1024                  // j-tile in LDS
#define NTILES (NPTS / TJ)       // 8
#define RPT (TJ / JT)            // 4 j-steps per thread per tile

typedef float f2_t __attribute__((ext_vector_type(2)));

// closeness^2 = exp(-100*d2) = exp2(C1*(ni+nj) + K2*dot6)
#define C1f (-144.26950408889634f)   // -100*log2(e)
#define K2f (288.53900817779268f)    // -2*C1
// out = s*exp(-20*pen) = s*exp2(C2*pen)
#define C2f (-28.853900817779268f)

__global__ __launch_bounds__(BLOCK, 4) void softnms_kernel(
    const float* __restrict__ src, const float* __restrict__ tgt,
    const float* __restrict__ scores, float* __restrict__ out)
{
    __shared__ float4 la[TJ];            // (K2*ax, K2*ay, K2*az, K2*bx)  16 KB
    __shared__ float4 lb[TJ];            // (K2*by, K2*bz, sj, C1*nj)     16 KB
    __shared__ float  lid[IBLK * 7];     // i-data broadcast
    __shared__ float  red[8 * IPT];      // per-wave partial sums

    const int t    = threadIdx.x;
    const int tj   = t & (JT - 1);       // j-lane within half
    const int half = t >> 8;             // which i-half this thread owns
    const int i0   = blockIdx.x * IBLK;
    const int kb   = half * IPT;

    // stage i-data through LDS so it lands in VGPRs
    if (t < IBLK) {
        int i = i0 + t;
        lid[t * 7 + 0] = src[i * 3 + 0];
        lid[t * 7 + 1] = src[i * 3 + 1];
        lid[t * 7 + 2] = src[i * 3 + 2];
        lid[t * 7 + 3] = tgt[i * 3 + 0];
        lid[t * 7 + 4] = tgt[i * 3 + 1];
        lid[t * 7 + 5] = tgt[i * 3 + 2];
        lid[t * 7 + 6] = scores[i];
    }
    __syncthreads();

    f2_t v0[IPT], v1[IPT], v2[IPT];
    float ci[IPT], si[IPT], acc[IPT];
    #pragma unroll
    for (int k = 0; k < IPT; k++) {
        float px = lid[(kb + k) * 7 + 0];
        float py = lid[(kb + k) * 7 + 1];
        float pz = lid[(kb + k) * 7 + 2];
        float qx = lid[(kb + k) * 7 + 3];
        float qy = lid[(kb + k) * 7 + 4];
        float qz = lid[(kb + k) * 7 + 5];
        v0[k].x = px; v0[k].y = py;
        v1[k].x = pz; v1[k].y = qx;
        v2[k].x = qy; v2[k].y = qz;
        ci[k] = C1f * (px * px + py * py + pz * pz
                     + qx * qx + qy * qy + qz * qz);
        si[k]  = lid[(kb + k) * 7 + 6];
        acc[k] = 0.0f;
    }

    for (int tile = 0; tile < NTILES; tile++) {
        const int j0 = tile * TJ;

        // ---- stage j-tile: pre-scale by K2, precompute cj = C1*nj ----
        #pragma unroll
        for (int r = 0; r < TJ / BLOCK; r++) {   // 2
            int jl = r * BLOCK + t;
            int j  = j0 + jl;
            float ax = src[j * 3 + 0];
            float ay = src[j * 3 + 1];
            float az = src[j * 3 + 2];
            float bx = tgt[j * 3 + 0];
            float by = tgt[j * 3 + 1];
            float bz = tgt[j * 3 + 2];
            float sj = scores[j];
            float nj = ax * ax + ay * ay + az * az
                     + bx * bx + by * by + bz * bz;
            la[jl] = make_float4(K2f * ax, K2f * ay, K2f * az, K2f * bx);
            lb[jl] = make_float4(K2f * by, K2f * bz, sj, C1f * nj);
        }
        __syncthreads();

        // ---- compute: RPT j's per thread, IPT i's each ----
        #pragma unroll
        for (int r = 0; r < RPT; r++) {
            const int j = r * JT + tj;
            float4 a = la[j];
            float4 b = lb[j];
            f2_t b0; b0.x = a.x; b0.y = a.y;
            f2_t b1; b1.x = a.z; b1.y = a.w;
            f2_t b2; b2.x = b.x; b2.y = b.y;
            float sj = b.z;
            float cj = b.w;
            #pragma unroll
            for (int k = 0; k < IPT; k++) {
                f2_t d = v0[k] * b0;
                d += v1[k] * b1;
                d += v2[k] * b2;
                float arg = d.x + d.y + ci[k] + cj;
                float cl  = __builtin_amdgcn_exp2f(arg);
                acc[k] += (sj > si[k]) ? cl : 0.0f;
            }
        }
        __syncthreads();
    }

    // ---- reduce within wave, then across waves; finalize inline ----
    const int lane = t & 63;
    const int wid  = t >> 6;     // 0..7 (waves 0-3 = half 0, 4-7 = half 1)
    #pragma unroll
    for (int k = 0; k < IPT; k++) {
        float v = acc[k];
        v += __shfl_xor(v, 32);
        v += __shfl_xor(v, 16);
        v += __shfl_xor(v, 8);
        v += __shfl_xor(v, 4);
        v += __shfl_xor(v, 2);
        v += __shfl_xor(v, 1);
        if (lane == 0) red[wid * IPT + k] = v;
    }
    __syncthreads();
    if (t < IBLK) {
        int h = t >> 3;          // owning half
        int k = t & 7;
        float p = red[(h * 4 + 0) * IPT + k]
                + red[(h * 4 + 1) * IPT + k]
                + red[(h * 4 + 2) * IPT + k]
                + red[(h * 4 + 3) * IPT + k];
        out[i0 + t] = scores[i0 + t] * __builtin_amdgcn_exp2f(C2f * p);
    }
}

extern "C" void kernel_launch(void* const* d_in, const int* in_sizes, int n_in,
                              void* d_out, int out_size, void* d_ws, size_t ws_size,
                              hipStream_t stream) {
    const float* src    = (const float*)d_in[0];
    const float* tgt    = (const float*)d_in[1];
    const float* scores = (const float*)d_in[2];
    float* out = (float*)d_out;

    softnms_kernel<<<NBLK, BLOCK, 0, stream>>>(src, tgt, scores, out);
}